// Round 12
// baseline (387.407 us; speedup 1.0000x reference)
//
#include <hip/hip_runtime.h>
#include <hip/hip_bf16.h>

#define NPTS  60000
#define KK    27
#define NEDGE 960000
#define CAP   96

typedef __attribute__((ext_vector_type(8))) short bf16x8;
typedef __attribute__((ext_vector_type(4))) float f32x4;

__device__ __forceinline__ unsigned short f2bf(float x) {
    unsigned u = __float_as_uint(x);
    return (unsigned short)((u + 0x7FFFu + ((u >> 16) & 1u)) >> 16);
}

union U8 { bf16x8 v; unsigned u[4]; };

// split 8 floats into bf16 hi + bf16 residual via v_cvt_pk_bf16_f32
__device__ __forceinline__ void split8(float4 a, float4 b, bf16x8& hi, bf16x8& lo) {
    float av[8] = {a.x, a.y, a.z, a.w, b.x, b.y, b.z, b.w};
    U8 h, l;
#pragma unroll
    for (int p = 0; p < 4; ++p) {
        float x0 = av[2 * p], x1 = av[2 * p + 1];
        unsigned hp;
        asm("v_cvt_pk_bf16_f32 %0, %1, %2" : "=v"(hp) : "v"(x0), "v"(x1));
        float hf0 = __uint_as_float(hp << 16);
        float hf1 = __uint_as_float(hp & 0xFFFF0000u);
        float r0 = x0 - hf0, r1 = x1 - hf1;
        unsigned lp;
        asm("v_cvt_pk_bf16_f32 %0, %1, %2" : "=v"(lp) : "v"(r0), "v"(r1));
        h.u[p] = hp; l.u[p] = lp;
    }
    hi = h.v; lo = l.v;
}

// ---------------------------------------------------------------------------
// tiny MLP: h2 = relu(bn2(relu(bn1(np@w1)) @ w2))  -> global [N][128]
// ---------------------------------------------------------------------------
__global__ __launch_bounds__(256) void tiny_mlp_kernel(
    const float* __restrict__ npnts,
    const float* __restrict__ w1, const float* __restrict__ bn1s, const float* __restrict__ bn1h,
    const float* __restrict__ w2, const float* __restrict__ bn2s, const float* __restrict__ bn2h,
    float* __restrict__ h2out) {
    __shared__ float w2s[3 * 128];
    __shared__ float sc2[128], sh2[128];
    __shared__ float w1s[9], sc1[3], sh1[3];
    __shared__ float h2s[64 * 129];

    const int tid = threadIdx.x;
    for (int i = tid; i < 384; i += 256) w2s[i] = w2[i];
    if (tid < 128) { sc2[tid] = bn2s[tid]; sh2[tid] = bn2h[tid]; }
    if (tid < 9) w1s[tid] = w1[tid];
    if (tid < 3) { sc1[tid] = bn1s[tid]; sh1[tid] = bn1h[tid]; }
    __syncthreads();

    const int p  = tid >> 2;
    const int cq = (tid & 3) * 32;
    const int pt = blockIdx.x * 64 + p;
    float h1a = 0.f, h1b = 0.f, h1c = 0.f;
    if (pt < NPTS) {
        float p0 = npnts[pt * 3 + 0], p1 = npnts[pt * 3 + 1], p2 = npnts[pt * 3 + 2];
        float t0 = p0 * w1s[0] + p1 * w1s[3] + p2 * w1s[6];
        float t1 = p0 * w1s[1] + p1 * w1s[4] + p2 * w1s[7];
        float t2 = p0 * w1s[2] + p1 * w1s[5] + p2 * w1s[8];
        h1a = fmaxf(t0 * sc1[0] + sh1[0], 0.f);
        h1b = fmaxf(t1 * sc1[1] + sh1[1], 0.f);
        h1c = fmaxf(t2 * sc1[2] + sh1[2], 0.f);
    }
    for (int c = cq; c < cq + 32; ++c) {
        float t = h1a * w2s[c] + h1b * w2s[128 + c] + h1c * w2s[256 + c];
        h2s[p * 129 + c] = fmaxf(t * sc2[c] + sh2[c], 0.f);
    }
    __syncthreads();
    for (int i = tid; i < 64 * 128; i += 256) {
        int row = i >> 7, col = i & 127;
        int gr = blockIdx.x * 64 + row;
        if (gr < NPTS) h2out[gr * 128 + col] = h2s[row * 129 + col];
    }
}

// ---------------------------------------------------------------------------
// Pack all 4 weight matrices into fragment-ordered bf16 hi/lo global images.
// o = ks[13:12] t[11:9] q[8:7] c16[6:3] s[2:0];
// element = w[(ks*32+q*8+s) * 128 + (t*16+c16)].
// ---------------------------------------------------------------------------
__global__ __launch_bounds__(256) void pack_w_kernel(
    const float* __restrict__ w3, const float* __restrict__ wq,
    const float* __restrict__ wv, const float* __restrict__ wo,
    short* __restrict__ hi, short* __restrict__ lo) {
    const float* srcs[4] = {w3, wq, wv, wo};
    const float* w = srcs[blockIdx.y];
    short* whi = hi + blockIdx.y * 16384;
    short* wlo = lo + blockIdx.y * 16384;
    int base = (blockIdx.x * 256 + threadIdx.x) * 4;
#pragma unroll
    for (int j = 0; j < 4; ++j) {
        int o   = base + j;
        int s   = o & 7;
        int c16 = (o >> 3) & 15;
        int q   = (o >> 7) & 3;
        int t   = (o >> 9) & 7;
        int ks  = (o >> 12) & 3;
        float x = w[(ks * 32 + q * 8 + s) * 128 + (t * 16 + c16)];
        unsigned short h = f2bf(x);
        float hf = __uint_as_float((unsigned)h << 16);
        whi[o] = (short)h;
        wlo[o] = (short)f2bf(x - hf);
    }
}

// ---------------------------------------------------------------------------
// Split-bf16 MFMA GEMM (R7 structure; ONLY change: B fragments read directly
// from the packed global images instead of an LDS copy — values identical).
// Block = 128 rows, 4 waves; wave = 2 row-tiles of 16 sharing B fragments.
// C/D layout (m89-verified): col = lane&15, row = (lane>>4)*4 + reg.
// MODE: 0 plain, 1 +residual, 2 per-16col-head l2norm.
// ---------------------------------------------------------------------------
template <int MODE>
__global__ __launch_bounds__(256, 2) void mfma_gemm_kernel(
    const float* __restrict__ in,
    const short* __restrict__ whi_g, const short* __restrict__ wlo_g,
    const float* __restrict__ bias, const float* __restrict__ resid,
    float* __restrict__ out) {
    const int tid  = threadIdx.x;
    const int lane = tid & 63;
    const int wv   = tid >> 6;
    const int q    = lane >> 4;
    const int cl   = lane & 15;
    const int rowbase = blockIdx.x * 128 + wv * 32;

    const bf16x8* BH = (const bf16x8*)whi_g;
    const bf16x8* BL = (const bf16x8*)wlo_g;
    const float* inA0 = &in[(size_t)min(rowbase + cl,      NPTS - 1) * 128];
    const float* inA1 = &in[(size_t)min(rowbase + 16 + cl, NPTS - 1) * 128];

    f32x4 acc[2][8];
#pragma unroll
    for (int u = 0; u < 2; ++u)
#pragma unroll
        for (int t = 0; t < 8; ++t) acc[u][t] = (f32x4){0.f, 0.f, 0.f, 0.f};

#pragma unroll
    for (int ks = 0; ks < 4; ++ks) {
        float4 a0a = *(const float4*)&inA0[ks * 32 + q * 8];
        float4 a0b = *(const float4*)&inA0[ks * 32 + q * 8 + 4];
        float4 a1a = *(const float4*)&inA1[ks * 32 + q * 8];
        float4 a1b = *(const float4*)&inA1[ks * 32 + q * 8 + 4];
        bf16x8 ah0, al0, ah1, al1;
        split8(a0a, a0b, ah0, al0);
        split8(a1a, a1b, ah1, al1);
#pragma unroll
        for (int t = 0; t < 8; ++t) {
            const int fi = ((ks * 8 + t) * 4 + q) * 16 + cl;
            bf16x8 bh = BH[fi];
            bf16x8 bl = BL[fi];
            acc[0][t] = __builtin_amdgcn_mfma_f32_16x16x32_bf16(ah0, bh, acc[0][t], 0, 0, 0);
            acc[0][t] = __builtin_amdgcn_mfma_f32_16x16x32_bf16(al0, bh, acc[0][t], 0, 0, 0);
            acc[0][t] = __builtin_amdgcn_mfma_f32_16x16x32_bf16(ah0, bl, acc[0][t], 0, 0, 0);
            acc[1][t] = __builtin_amdgcn_mfma_f32_16x16x32_bf16(ah1, bh, acc[1][t], 0, 0, 0);
            acc[1][t] = __builtin_amdgcn_mfma_f32_16x16x32_bf16(al1, bh, acc[1][t], 0, 0, 0);
            acc[1][t] = __builtin_amdgcn_mfma_f32_16x16x32_bf16(ah1, bl, acc[1][t], 0, 0, 0);
        }
    }

    float breg[8];
#pragma unroll
    for (int t = 0; t < 8; ++t) breg[t] = bias[t * 16 + cl];

#pragma unroll
    for (int u = 0; u < 2; ++u) {
#pragma unroll
        for (int t = 0; t < 8; ++t) {
#pragma unroll
            for (int r = 0; r < 4; ++r) {
                int row = rowbase + u * 16 + q * 4 + r;
                float o = acc[u][t][r] + breg[t];
                if (MODE == 1) {
                    if (row < NPTS) o += resid[row * 128 + t * 16 + cl];
                }
                if (MODE == 2) {
                    float ss = o * o;
                    ss += __shfl_xor(ss, 1);
                    ss += __shfl_xor(ss, 2);
                    ss += __shfl_xor(ss, 4);
                    ss += __shfl_xor(ss, 8);
                    o *= 1.f / fmaxf(sqrtf(ss), 1e-12f);
                }
                if (row < NPTS) out[row * 128 + t * 16 + cl] = o;
            }
        }
    }
}

// ---------------------------------------------------------------------------
// Bucketing (int32 index inputs). Packed record: (key_idx << 5) | koff
// ---------------------------------------------------------------------------
__global__ __launch_bounds__(256) void zero_cnt_kernel(int* __restrict__ cnt) {
    int i = blockIdx.x * 256 + threadIdx.x;
    if (i < NPTS) cnt[i] = 0;
}

__global__ __launch_bounds__(256) void build_buckets_kernel(
    const int* __restrict__ r0, const int* __restrict__ r1,
    int* __restrict__ cnt, int* __restrict__ bucket) {
    int m = blockIdx.x * 256 + threadIdx.x;
    if (m >= NEDGE) return;
    int a = r0[m];
    int q = r1[m];
    if (q < 0 || q >= NPTS) return;
    if (a < 0 || a >= NPTS * KK) return;
    int kidx = a / KK;
    int koff = a - kidx * KK;
    int slot = atomicAdd(&cnt[q], 1);
    if (slot < CAP) bucket[q * CAP + slot] = (kidx << 5) | koff;
}

// ---------------------------------------------------------------------------
// attn+scatter (R7-verified): one wave per query. Lane l owns channels
// 2l,2l+1 (head l/8). Records cached lane-parallel, shfl-extracted.
// ---------------------------------------------------------------------------
__global__ __launch_bounds__(256, 8) void attn_scatter_kernel(
    const float* __restrict__ nq, const float* __restrict__ v,
    const float* __restrict__ pos_enc, const int* __restrict__ cnt,
    const int* __restrict__ bucket, float* __restrict__ pre) {
    __shared__ float nps[KK * 128];

    const int tid = threadIdx.x;
    if (tid < KK * 8) {
        const float4* pv = (const float4*)&pos_enc[tid * 16];
        float4 a = pv[0], b = pv[1], c = pv[2], d = pv[3];
        float ss = a.x*a.x + a.y*a.y + a.z*a.z + a.w*a.w
                 + b.x*b.x + b.y*b.y + b.z*b.z + b.w*b.w
                 + c.x*c.x + c.y*c.y + c.z*c.z + c.w*c.w
                 + d.x*d.x + d.y*d.y + d.z*d.z + d.w*d.w;
        float inv = 1.f / fmaxf(sqrtf(ss), 1e-12f);
        float4* o = (float4*)&nps[tid * 16];
        o[0] = make_float4(a.x*inv, a.y*inv, a.z*inv, a.w*inv);
        o[1] = make_float4(b.x*inv, b.y*inv, b.z*inv, b.w*inv);
        o[2] = make_float4(c.x*inv, c.y*inv, c.z*inv, c.w*inv);
        o[3] = make_float4(d.x*inv, d.y*inv, d.z*inv, d.w*inv);
    }
    __syncthreads();

    const int l = tid & 63;
    const int wid = blockIdx.x * 4 + (tid >> 6);
    const int nwaves = gridDim.x * 4;

#define ATT_EDGE(REC) do {                                                  \
        int koff_ = (REC) & 31; int kidx_ = (REC) >> 5;                     \
        float2 np_ = *(const float2*)&nps[koff_ * 128 + 2 * l];             \
        float2 v_  = *(const float2*)&v[kidx_ * 128 + 2 * l];               \
        float a_ = nq2.x * np_.x + nq2.y * np_.y;                           \
        a_ += __shfl_xor(a_, 1); a_ += __shfl_xor(a_, 2);                   \
        a_ += __shfl_xor(a_, 4);                                            \
        accx = fmaf(a_, v_.x, accx); accy = fmaf(a_, v_.y, accy);           \
    } while (0)

    for (int n = wid; n < NPTS; n += nwaves) {
        float2 nq2 = *(const float2*)&nq[n * 128 + 2 * l];
        int deg = min(cnt[n], CAP);
        int base = n * CAP;
        int myrec = (l < deg) ? bucket[base + l] : 0;
        float accx = 0.f, accy = 0.f;
        int dmain = min(deg, 64);
        int e = 0;
        for (; e + 4 <= dmain; e += 4) {
            int r0 = __shfl(myrec, e);
            int r1 = __shfl(myrec, e + 1);
            int r2 = __shfl(myrec, e + 2);
            int r3 = __shfl(myrec, e + 3);
            ATT_EDGE(r0); ATT_EDGE(r1); ATT_EDGE(r2); ATT_EDGE(r3);
        }
        for (; e < dmain; ++e) {
            int r = __shfl(myrec, e);
            ATT_EDGE(r);
        }
        for (; e < deg; ++e) {
            int r = bucket[base + e];
            ATT_EDGE(r);
        }
        *(float2*)&pre[n * 128 + 2 * l] = make_float2(accx, accy);
    }
#undef ATT_EDGE
}

// ---------------------------------------------------------------------------
extern "C" void kernel_launch(void* const* d_in, const int* in_sizes, int n_in,
                              void* d_out, int out_size, void* d_ws, size_t ws_size,
                              hipStream_t stream) {
    const float* feats = (const float*)d_in[0];
    const float* npnts = (const float*)d_in[1];
    const float* w1    = (const float*)d_in[2];
    const float* bn1s  = (const float*)d_in[3];
    const float* bn1h  = (const float*)d_in[4];
    const float* w2    = (const float*)d_in[5];
    const float* bn2s  = (const float*)d_in[6];
    const float* bn2h  = (const float*)d_in[7];
    const float* w3    = (const float*)d_in[8];
    const float* b3    = (const float*)d_in[9];
    const float* wq    = (const float*)d_in[10];
    const float* bq    = (const float*)d_in[11];
    const float* wv    = (const float*)d_in[12];
    const float* bv    = (const float*)d_in[13];
    const float* wo    = (const float*)d_in[14];
    const float* bo    = (const float*)d_in[15];
    const float* pos   = (const float*)d_in[16];
    const int*   r0    = (const int*)d_in[17];
    const int*   r1    = (const int*)d_in[18];
    float* out = (float*)d_out;

    // Workspace: 4 regions of NPTS*128 floats + packed-W images (256 KB).
    float* h2buf = (float*)d_ws;
    float* xbuf  = h2buf + (size_t)NPTS * 128;
    float* nqbuf = xbuf  + (size_t)NPTS * 128;
    float* vbuf  = nqbuf + (size_t)NPTS * 128;
    short* whi_g = (short*)(vbuf + (size_t)NPTS * 128);
    short* wlo_g = whi_g + 4 * 16384;
    float* prebuf = xbuf;                       // alias: x dead after q/v proj
    int*   cnt    = (int*)h2buf;                // alias: h2 dead after x-GEMM
    int*   bucket = cnt + NPTS;

    dim3 blk(256);
    const int nb64  = (NPTS + 63) / 64;         // 938
    const int nb128 = (NPTS + 127) / 128;       // 469

    pack_w_kernel<<<dim3(16, 4), blk, 0, stream>>>(w3, wq, wv, wo, whi_g, wlo_g);
    tiny_mlp_kernel<<<nb64, blk, 0, stream>>>(npnts, w1, bn1s, bn1h, w2, bn2s, bn2h, h2buf);
    mfma_gemm_kernel<1><<<nb128, blk, 0, stream>>>(h2buf, whi_g,             wlo_g,             b3, feats, xbuf);
    mfma_gemm_kernel<2><<<nb128, blk, 0, stream>>>(xbuf,  whi_g + 16384,     wlo_g + 16384,     bq, nullptr, nqbuf);
    mfma_gemm_kernel<0><<<nb128, blk, 0, stream>>>(xbuf,  whi_g + 2 * 16384, wlo_g + 2 * 16384, bv, nullptr, vbuf);
    zero_cnt_kernel<<<(NPTS + 255) / 256, blk, 0, stream>>>(cnt);
    build_buckets_kernel<<<(NEDGE + 255) / 256, blk, 0, stream>>>(r0, r1, cnt, bucket);
    attn_scatter_kernel<<<2048, blk, 0, stream>>>(nqbuf, vbuf, pos, cnt, bucket, prebuf);
    mfma_gemm_kernel<0><<<nb128, blk, 0, stream>>>(prebuf, whi_g + 3 * 16384, wlo_g + 3 * 16384, bo, nullptr, out);
}

// Round 13
// 353.263 us; speedup vs baseline: 1.0967x; 1.0967x over previous
//
#include <hip/hip_runtime.h>
#include <hip/hip_bf16.h>

#define NPTS  60000
#define KK    27
#define NEDGE 960000
#define CAP   96

typedef __attribute__((ext_vector_type(8))) short bf16x8;
typedef __attribute__((ext_vector_type(4))) float f32x4;

__device__ __forceinline__ unsigned short f2bf(float x) {
    unsigned u = __float_as_uint(x);
    return (unsigned short)((u + 0x7FFFu + ((u >> 16) & 1u)) >> 16);
}

union U8 { bf16x8 v; unsigned u[4]; };

// split 8 floats into bf16 hi + bf16 residual via v_cvt_pk_bf16_f32
__device__ __forceinline__ void split8(float4 a, float4 b, bf16x8& hi, bf16x8& lo) {
    float av[8] = {a.x, a.y, a.z, a.w, b.x, b.y, b.z, b.w};
    U8 h, l;
#pragma unroll
    for (int p = 0; p < 4; ++p) {
        float x0 = av[2 * p], x1 = av[2 * p + 1];
        unsigned hp;
        asm("v_cvt_pk_bf16_f32 %0, %1, %2" : "=v"(hp) : "v"(x0), "v"(x1));
        float hf0 = __uint_as_float(hp << 16);
        float hf1 = __uint_as_float(hp & 0xFFFF0000u);
        float r0 = x0 - hf0, r1 = x1 - hf1;
        unsigned lp;
        asm("v_cvt_pk_bf16_f32 %0, %1, %2" : "=v"(lp) : "v"(r0), "v"(r1));
        h.u[p] = hp; l.u[p] = lp;
    }
    hi = h.v; lo = l.v;
}

// ---------------------------------------------------------------------------
// prep: blocks 0..63 pack the 4 weight matrices into fragment-ordered bf16
// hi/lo images; blocks 64.. zero the cnt array.
// o = ks[13:12] t[11:9] q[8:7] c16[6:3] s[2:0]; elem = w[(ks*32+q*8+s)*128 + t*16+c16]
// ---------------------------------------------------------------------------
__global__ __launch_bounds__(256) void prep_kernel(
    const float* __restrict__ w3, const float* __restrict__ wq,
    const float* __restrict__ wv, const float* __restrict__ wo,
    short* __restrict__ hi, short* __restrict__ lo, int* __restrict__ cnt) {
    const int b = blockIdx.x;
    const int tid = threadIdx.x;
    if (b < 64) {
        const float* srcs[4] = {w3, wq, wv, wo};
        const int mat = b >> 4;
        const float* w = srcs[mat];
        short* whi = hi + mat * 16384;
        short* wlo = lo + mat * 16384;
        int base = ((b & 15) * 256 + tid) * 4;
#pragma unroll
        for (int j = 0; j < 4; ++j) {
            int o   = base + j;
            int s   = o & 7;
            int c16 = (o >> 3) & 15;
            int q   = (o >> 7) & 3;
            int t   = (o >> 9) & 7;
            int ks  = (o >> 12) & 3;
            float x = w[(ks * 32 + q * 8 + s) * 128 + (t * 16 + c16)];
            unsigned short h = f2bf(x);
            float hf = __uint_as_float((unsigned)h << 16);
            whi[o] = (short)h;
            wlo[o] = (short)f2bf(x - hf);
        }
    } else {
        int i = (b - 64) * 256 + tid;
        if (i < NPTS) cnt[i] = 0;
    }
}

// ---------------------------------------------------------------------------
// Fused tiny-MLP + x-GEMM: per 64-row block, compute h2 tile into LDS
// [64][132] (pad -> 2-way-free banks), then split-bf16 MFMA GEMM with
// B fragments from the packed global image. Epilogue adds b3 + feats.
// C/D layout (m89-verified): col = lane&15, row = (lane>>4)*4 + reg.
// ---------------------------------------------------------------------------
__global__ __launch_bounds__(256, 2) void xgemm_mlp_kernel(
    const float* __restrict__ npnts,
    const float* __restrict__ w1, const float* __restrict__ bn1s, const float* __restrict__ bn1h,
    const float* __restrict__ w2, const float* __restrict__ bn2s, const float* __restrict__ bn2h,
    const short* __restrict__ whi_g, const short* __restrict__ wlo_g,
    const float* __restrict__ b3, const float* __restrict__ feats,
    float* __restrict__ xout) {
    __shared__ float h2s[64][132];
    __shared__ float w2s[3 * 128];
    __shared__ float sc2[128], sh2[128];
    __shared__ float w1s[9], sc1[3], sh1[3];

    const int tid = threadIdx.x;
    for (int i = tid; i < 384; i += 256) w2s[i] = w2[i];
    if (tid < 128) { sc2[tid] = bn2s[tid]; sh2[tid] = bn2h[tid]; }
    if (tid < 9) w1s[tid] = w1[tid];
    if (tid < 3) { sc1[tid] = bn1s[tid]; sh1[tid] = bn1h[tid]; }
    __syncthreads();

    {   // tiny MLP -> h2 tile (rows past NPTS: h1=0, values unused)
        const int p  = tid >> 2;
        const int cq = (tid & 3) * 32;
        const int pt = blockIdx.x * 64 + p;
        float h1a = 0.f, h1b = 0.f, h1c = 0.f;
        if (pt < NPTS) {
            float p0 = npnts[pt * 3 + 0], p1 = npnts[pt * 3 + 1], p2 = npnts[pt * 3 + 2];
            float t0 = p0 * w1s[0] + p1 * w1s[3] + p2 * w1s[6];
            float t1 = p0 * w1s[1] + p1 * w1s[4] + p2 * w1s[7];
            float t2 = p0 * w1s[2] + p1 * w1s[5] + p2 * w1s[8];
            h1a = fmaxf(t0 * sc1[0] + sh1[0], 0.f);
            h1b = fmaxf(t1 * sc1[1] + sh1[1], 0.f);
            h1c = fmaxf(t2 * sc1[2] + sh1[2], 0.f);
        }
        for (int c = cq; c < cq + 32; ++c) {
            float t = h1a * w2s[c] + h1b * w2s[128 + c] + h1c * w2s[256 + c];
            h2s[p][c] = fmaxf(t * sc2[c] + sh2[c], 0.f);
        }
    }
    __syncthreads();

    const int lane = tid & 63;
    const int wv   = tid >> 6;
    const int q    = lane >> 4;
    const int cl   = lane & 15;
    const int row0 = blockIdx.x * 64 + wv * 16;
    const int trow = wv * 16 + cl;              // row within LDS tile

    const bf16x8* BH = (const bf16x8*)whi_g;
    const bf16x8* BL = (const bf16x8*)wlo_g;

    f32x4 acc[8];
#pragma unroll
    for (int t = 0; t < 8; ++t) acc[t] = (f32x4){0.f, 0.f, 0.f, 0.f};

#pragma unroll
    for (int ks = 0; ks < 4; ++ks) {
        float4 aa = *(const float4*)&h2s[trow][ks * 32 + q * 8];
        float4 ab = *(const float4*)&h2s[trow][ks * 32 + q * 8 + 4];
        bf16x8 ah, al;
        split8(aa, ab, ah, al);
#pragma unroll
        for (int t = 0; t < 8; ++t) {
            const int fi = ((ks * 8 + t) * 4 + q) * 16 + cl;
            bf16x8 bh = BH[fi];
            bf16x8 bl = BL[fi];
            acc[t] = __builtin_amdgcn_mfma_f32_16x16x32_bf16(ah, bh, acc[t], 0, 0, 0);
            acc[t] = __builtin_amdgcn_mfma_f32_16x16x32_bf16(al, bh, acc[t], 0, 0, 0);
            acc[t] = __builtin_amdgcn_mfma_f32_16x16x32_bf16(ah, bl, acc[t], 0, 0, 0);
        }
    }

#pragma unroll
    for (int t = 0; t < 8; ++t) {
        float bv_ = b3[t * 16 + cl];
#pragma unroll
        for (int r = 0; r < 4; ++r) {
            int row = row0 + q * 4 + r;
            if (row < NPTS) {
                float o = acc[t][r] + bv_ + feats[row * 128 + t * 16 + cl];
                xout[row * 128 + t * 16 + cl] = o;
            }
        }
    }
}

// ---------------------------------------------------------------------------
// Fused q/v projection (SAFE 256-VGPR budget): reads x once, writes nq
// (per-head l2norm) and v. 64-row blocks, wave = 16 rows.
// ---------------------------------------------------------------------------
__global__ __launch_bounds__(256, 2) void mfma_gemm_qv_kernel(
    const float* __restrict__ in,
    const short* __restrict__ whq, const short* __restrict__ wlq,
    const short* __restrict__ whv, const short* __restrict__ wlv,
    const float* __restrict__ bq, const float* __restrict__ bv,
    float* __restrict__ nqout, float* __restrict__ vout) {
    const int tid  = threadIdx.x;
    const int lane = tid & 63;
    const int wv   = tid >> 6;
    const int q    = lane >> 4;
    const int cl   = lane & 15;
    const int row0 = blockIdx.x * 64 + wv * 16;
    const int arow = min(row0 + cl, NPTS - 1);

    const bf16x8* QH = (const bf16x8*)whq;
    const bf16x8* QL = (const bf16x8*)wlq;
    const bf16x8* VH = (const bf16x8*)whv;
    const bf16x8* VL = (const bf16x8*)wlv;
    const float*  A  = &in[(size_t)arow * 128];

    f32x4 accq[8], accv[8];
#pragma unroll
    for (int t = 0; t < 8; ++t) {
        accq[t] = (f32x4){0.f, 0.f, 0.f, 0.f};
        accv[t] = (f32x4){0.f, 0.f, 0.f, 0.f};
    }

#pragma unroll
    for (int ks = 0; ks < 4; ++ks) {
        float4 aa = *(const float4*)&A[ks * 32 + q * 8];
        float4 ab = *(const float4*)&A[ks * 32 + q * 8 + 4];
        bf16x8 ah, al;
        split8(aa, ab, ah, al);
#pragma unroll
        for (int t = 0; t < 8; ++t) {
            const int fi = ((ks * 8 + t) * 4 + q) * 16 + cl;
            bf16x8 qh = QH[fi], ql = QL[fi];
            bf16x8 vh = VH[fi], vl = VL[fi];
            accq[t] = __builtin_amdgcn_mfma_f32_16x16x32_bf16(ah, qh, accq[t], 0, 0, 0);
            accq[t] = __builtin_amdgcn_mfma_f32_16x16x32_bf16(al, qh, accq[t], 0, 0, 0);
            accq[t] = __builtin_amdgcn_mfma_f32_16x16x32_bf16(ah, ql, accq[t], 0, 0, 0);
            accv[t] = __builtin_amdgcn_mfma_f32_16x16x32_bf16(ah, vh, accv[t], 0, 0, 0);
            accv[t] = __builtin_amdgcn_mfma_f32_16x16x32_bf16(al, vh, accv[t], 0, 0, 0);
            accv[t] = __builtin_amdgcn_mfma_f32_16x16x32_bf16(ah, vl, accv[t], 0, 0, 0);
        }
    }

#pragma unroll
    for (int t = 0; t < 8; ++t) {
        float bq_ = bq[t * 16 + cl];
        float bv_ = bv[t * 16 + cl];
#pragma unroll
        for (int r = 0; r < 4; ++r) {
            int row = row0 + q * 4 + r;
            float oq = accq[t][r] + bq_;
            float ov = accv[t][r] + bv_;
            float ss = oq * oq;
            ss += __shfl_xor(ss, 1);
            ss += __shfl_xor(ss, 2);
            ss += __shfl_xor(ss, 4);
            ss += __shfl_xor(ss, 8);
            oq *= 1.f / fmaxf(sqrtf(ss), 1e-12f);
            if (row < NPTS) {
                nqout[row * 128 + t * 16 + cl] = oq;
                vout[row * 128 + t * 16 + cl]  = ov;
            }
        }
    }
}

// ---------------------------------------------------------------------------
// Plain split-bf16 MFMA GEMM (R12-verified), for the final wo projection.
// ---------------------------------------------------------------------------
__global__ __launch_bounds__(256, 2) void mfma_gemm_kernel(
    const float* __restrict__ in,
    const short* __restrict__ whi_g, const short* __restrict__ wlo_g,
    const float* __restrict__ bias, float* __restrict__ out) {
    const int tid  = threadIdx.x;
    const int lane = tid & 63;
    const int wv   = tid >> 6;
    const int q    = lane >> 4;
    const int cl   = lane & 15;
    const int rowbase = blockIdx.x * 128 + wv * 32;

    const bf16x8* BH = (const bf16x8*)whi_g;
    const bf16x8* BL = (const bf16x8*)wlo_g;
    const float* inA0 = &in[(size_t)min(rowbase + cl,      NPTS - 1) * 128];
    const float* inA1 = &in[(size_t)min(rowbase + 16 + cl, NPTS - 1) * 128];

    f32x4 acc[2][8];
#pragma unroll
    for (int u = 0; u < 2; ++u)
#pragma unroll
        for (int t = 0; t < 8; ++t) acc[u][t] = (f32x4){0.f, 0.f, 0.f, 0.f};

#pragma unroll
    for (int ks = 0; ks < 4; ++ks) {
        float4 a0a = *(const float4*)&inA0[ks * 32 + q * 8];
        float4 a0b = *(const float4*)&inA0[ks * 32 + q * 8 + 4];
        float4 a1a = *(const float4*)&inA1[ks * 32 + q * 8];
        float4 a1b = *(const float4*)&inA1[ks * 32 + q * 8 + 4];
        bf16x8 ah0, al0, ah1, al1;
        split8(a0a, a0b, ah0, al0);
        split8(a1a, a1b, ah1, al1);
#pragma unroll
        for (int t = 0; t < 8; ++t) {
            const int fi = ((ks * 8 + t) * 4 + q) * 16 + cl;
            bf16x8 bh = BH[fi];
            bf16x8 bl = BL[fi];
            acc[0][t] = __builtin_amdgcn_mfma_f32_16x16x32_bf16(ah0, bh, acc[0][t], 0, 0, 0);
            acc[0][t] = __builtin_amdgcn_mfma_f32_16x16x32_bf16(al0, bh, acc[0][t], 0, 0, 0);
            acc[0][t] = __builtin_amdgcn_mfma_f32_16x16x32_bf16(ah0, bl, acc[0][t], 0, 0, 0);
            acc[1][t] = __builtin_amdgcn_mfma_f32_16x16x32_bf16(ah1, bh, acc[1][t], 0, 0, 0);
            acc[1][t] = __builtin_amdgcn_mfma_f32_16x16x32_bf16(al1, bh, acc[1][t], 0, 0, 0);
            acc[1][t] = __builtin_amdgcn_mfma_f32_16x16x32_bf16(ah1, bl, acc[1][t], 0, 0, 0);
        }
    }

    float breg[8];
#pragma unroll
    for (int t = 0; t < 8; ++t) breg[t] = bias[t * 16 + cl];

#pragma unroll
    for (int u = 0; u < 2; ++u) {
#pragma unroll
        for (int t = 0; t < 8; ++t) {
#pragma unroll
            for (int r = 0; r < 4; ++r) {
                int row = rowbase + u * 16 + q * 4 + r;
                if (row < NPTS) out[row * 128 + t * 16 + cl] = acc[u][t][r] + breg[t];
            }
        }
    }
}

// ---------------------------------------------------------------------------
// Bucketing (int32 index inputs). Packed record: (key_idx << 5) | koff
// ---------------------------------------------------------------------------
__global__ __launch_bounds__(256) void build_buckets_kernel(
    const int* __restrict__ r0, const int* __restrict__ r1,
    int* __restrict__ cnt, int* __restrict__ bucket) {
    int m = blockIdx.x * 256 + threadIdx.x;
    if (m >= NEDGE) return;
    int a = r0[m];
    int q = r1[m];
    if (q < 0 || q >= NPTS) return;
    if (a < 0 || a >= NPTS * KK) return;
    int kidx = a / KK;
    int koff = a - kidx * KK;
    int slot = atomicAdd(&cnt[q], 1);
    if (slot < CAP) bucket[q * CAP + slot] = (kidx << 5) | koff;
}

// ---------------------------------------------------------------------------
// attn+scatter (R7/R12-verified): one wave per query. Lane l owns channels
// 2l,2l+1 (head l/8). Records cached lane-parallel, shfl-extracted.
// ---------------------------------------------------------------------------
__global__ __launch_bounds__(256, 8) void attn_scatter_kernel(
    const float* __restrict__ nq, const float* __restrict__ v,
    const float* __restrict__ pos_enc, const int* __restrict__ cnt,
    const int* __restrict__ bucket, float* __restrict__ pre) {
    __shared__ float nps[KK * 128];

    const int tid = threadIdx.x;
    if (tid < KK * 8) {
        const float4* pv = (const float4*)&pos_enc[tid * 16];
        float4 a = pv[0], b = pv[1], c = pv[2], d = pv[3];
        float ss = a.x*a.x + a.y*a.y + a.z*a.z + a.w*a.w
                 + b.x*b.x + b.y*b.y + b.z*b.z + b.w*b.w
                 + c.x*c.x + c.y*c.y + c.z*c.z + c.w*c.w
                 + d.x*d.x + d.y*d.y + d.z*d.z + d.w*d.w;
        float inv = 1.f / fmaxf(sqrtf(ss), 1e-12f);
        float4* o = (float4*)&nps[tid * 16];
        o[0] = make_float4(a.x*inv, a.y*inv, a.z*inv, a.w*inv);
        o[1] = make_float4(b.x*inv, b.y*inv, b.z*inv, b.w*inv);
        o[2] = make_float4(c.x*inv, c.y*inv, c.z*inv, c.w*inv);
        o[3] = make_float4(d.x*inv, d.y*inv, d.z*inv, d.w*inv);
    }
    __syncthreads();

    const int l = tid & 63;
    const int wid = blockIdx.x * 4 + (tid >> 6);
    const int nwaves = gridDim.x * 4;

#define ATT_EDGE(REC) do {                                                  \
        int koff_ = (REC) & 31; int kidx_ = (REC) >> 5;                     \
        float2 np_ = *(const float2*)&nps[koff_ * 128 + 2 * l];             \
        float2 v_  = *(const float2*)&v[kidx_ * 128 + 2 * l];               \
        float a_ = nq2.x * np_.x + nq2.y * np_.y;                           \
        a_ += __shfl_xor(a_, 1); a_ += __shfl_xor(a_, 2);                   \
        a_ += __shfl_xor(a_, 4);                                            \
        accx = fmaf(a_, v_.x, accx); accy = fmaf(a_, v_.y, accy);           \
    } while (0)

    for (int n = wid; n < NPTS; n += nwaves) {
        float2 nq2 = *(const float2*)&nq[n * 128 + 2 * l];
        int deg = min(cnt[n], CAP);
        int base = n * CAP;
        int myrec = (l < deg) ? bucket[base + l] : 0;
        float accx = 0.f, accy = 0.f;
        int dmain = min(deg, 64);
        int e = 0;
        for (; e + 4 <= dmain; e += 4) {
            int r0 = __shfl(myrec, e);
            int r1 = __shfl(myrec, e + 1);
            int r2 = __shfl(myrec, e + 2);
            int r3 = __shfl(myrec, e + 3);
            ATT_EDGE(r0); ATT_EDGE(r1); ATT_EDGE(r2); ATT_EDGE(r3);
        }
        for (; e < dmain; ++e) {
            int r = __shfl(myrec, e);
            ATT_EDGE(r);
        }
        for (; e < deg; ++e) {
            int r = bucket[base + e];
            ATT_EDGE(r);
        }
        *(float2*)&pre[n * 128 + 2 * l] = make_float2(accx, accy);
    }
#undef ATT_EDGE
}

// ---------------------------------------------------------------------------
extern "C" void kernel_launch(void* const* d_in, const int* in_sizes, int n_in,
                              void* d_out, int out_size, void* d_ws, size_t ws_size,
                              hipStream_t stream) {
    const float* feats = (const float*)d_in[0];
    const float* npnts = (const float*)d_in[1];
    const float* w1    = (const float*)d_in[2];
    const float* bn1s  = (const float*)d_in[3];
    const float* bn1h  = (const float*)d_in[4];
    const float* w2    = (const float*)d_in[5];
    const float* bn2s  = (const float*)d_in[6];
    const float* bn2h  = (const float*)d_in[7];
    const float* w3    = (const float*)d_in[8];
    const float* b3    = (const float*)d_in[9];
    const float* wq    = (const float*)d_in[10];
    const float* bq    = (const float*)d_in[11];
    const float* wv    = (const float*)d_in[12];
    const float* bv    = (const float*)d_in[13];
    const float* wo    = (const float*)d_in[14];
    const float* bo    = (const float*)d_in[15];
    const float* pos   = (const float*)d_in[16];
    const int*   r0    = (const int*)d_in[17];
    const int*   r1    = (const int*)d_in[18];
    float* out = (float*)d_out;

    // Workspace: x (later pre), nq, v, packed W images, cnt+bucket.
    float* xbuf  = (float*)d_ws;
    float* nqbuf = xbuf  + (size_t)NPTS * 128;
    float* vbuf  = nqbuf + (size_t)NPTS * 128;
    short* whi_g = (short*)(vbuf + (size_t)NPTS * 128);
    short* wlo_g = whi_g + 4 * 16384;
    int*   cnt    = (int*)(wlo_g + 4 * 16384);
    int*   bucket = cnt + NPTS;
    float* prebuf = xbuf;                       // alias: x dead after q/v proj

    dim3 blk(256);
    const int nb64  = (NPTS + 63) / 64;         // 938
    const int nb128 = (NPTS + 127) / 128;       // 469
    const int nprep = 64 + (NPTS + 255) / 256;  // 64 pack + 235 zero

    prep_kernel<<<nprep, blk, 0, stream>>>(w3, wq, wv, wo, whi_g, wlo_g, cnt);
    xgemm_mlp_kernel<<<nb64, blk, 0, stream>>>(npnts, w1, bn1s, bn1h, w2, bn2s, bn2h,
                                               whi_g, wlo_g, b3, feats, xbuf);
    mfma_gemm_qv_kernel<<<nb64, blk, 0, stream>>>(xbuf,
        whi_g + 16384, wlo_g + 16384, whi_g + 2 * 16384, wlo_g + 2 * 16384,
        bq, bv, nqbuf, vbuf);
    build_buckets_kernel<<<(NEDGE + 255) / 256, blk, 0, stream>>>(r0, r1, cnt, bucket);
    attn_scatter_kernel<<<2048, blk, 0, stream>>>(nqbuf, vbuf, pos, cnt, bucket, prebuf);
    mfma_gemm_kernel<<<nb128, blk, 0, stream>>>(prebuf, whi_g + 3 * 16384, wlo_g + 3 * 16384, bo, out);
}